// Round 6
// baseline (2149.170 us; speedup 1.0000x reference)
//
#include <hip/hip_runtime.h>
#include <hip/hip_bf16.h>
#include <math.h>

#define NATOMS 1024          // B*A
#define NGRID  6912          // B*NG
#define NNODES 7936
#define NG_PER 1728
#define KA 8
#define KG 32
#define CODE 64
#define HID 128

typedef __hip_bfloat16 bf16;

// Fallback workspace allocated at library load (legal: outside kernel_launch).
static void* g_buf = nullptr;
__attribute__((constructor)) static void _alloc_ws(){
  if (hipMalloc(&g_buf, (size_t)16 * 1024 * 1024) != hipSuccess) g_buf = nullptr;
}

__device__ __forceinline__ float tof(bf16 x){ return __bfloat162float(x); }

// dtype-agnostic float load: element i of buffer p, fp32 if f32!=0 else bf16
__device__ __forceinline__ float ldf(const void* p, size_t i, int f32){
  return f32 ? ((const float*)p)[i] : __bfloat162float(((const bf16*)p)[i]);
}

// dtype-agnostic int load: mode 0=int32, 1=int64(LE), 2=f32, 3=bf16
__device__ __forceinline__ int ldt(const void* p, int i, int mode){
  switch(mode){
    case 1:  return ((const int*)p)[2*i];
    case 2:  return (int)((const float*)p)[i];
    case 3:  return (int)__bfloat162float(((const bf16*)p)[i]);
    default: return ((const int*)p)[i];
  }
}

// ---------- detect input dtypes (pos float width, atom_types int width) ----------
__global__ void k_detect(const unsigned short* __restrict__ posu,
                         const unsigned short* __restrict__ typu,
                         int* __restrict__ flag){
  if (blockIdx.x == 0){
    __shared__ int scnt;
    int t = threadIdx.x;               // 256 threads
    if (t == 0) scnt = 0;
    __syncthreads();
    int c = 0;
    for (int q = 0; q < 12; q++){
      unsigned short u = posu[t + 256*q];
      int e = (u >> 7) & 0xFF;
      if (e >= 140) c++;
    }
    atomicAdd(&scnt, c);
    __syncthreads();
    if (t == 0) flag[0] = (scnt > 16) ? 1 : 0;
  } else if (threadIdx.x == 0){
    int oddHigh = 0, evenHigh = 0, quadZero = 1;
    for (int k = 0; k < 16; k++){
      unsigned short o = typu[2*k+1], e = typu[2*k];
      if (o >= 0x3F00 && o <= 0x4200) oddHigh++;
      if (e >= 0x3F00 && e <= 0x4200) evenHigh++;
    }
    for (int k = 0; k < 16; k++) if (typu[4*k+2] != 0) quadZero = 0;
    int mode;
    if (oddHigh >= 8) mode = (evenHigh >= 8) ? 3 : 2;   // bf16 : f32
    else              mode = quadZero ? 1 : 0;          // int64 : int32
    flag[1] = mode;
  }
}

// ---------- gaussian smearing constants, f64 (matches numpy float64 path) ----------
__global__ void k_consts(double* gcd){
  int k = threadIdx.x;
  if (k >= 20) return;
  double step = log(6.0) / 19.0;
  double offk = exp((double)k * step) - 1.0;
  int km = (k == 0) ? 1 : k;
  double d = (exp((double)km * step) - 1.0) - (exp((double)(km - 1) * step) - 1.0);
  gcd[k]      = offk;
  gcd[20 + k] = -0.5 / (d * d);
}

// ---------- node_pos (f32 + f64) + h0 (one-hot atoms, zero grid) ----------
__global__ void k_init(const void* __restrict__ pos, const void* __restrict__ types,
                       const int* __restrict__ flag,
                       float* __restrict__ node_pos, double* __restrict__ npd,
                       float* __restrict__ h0){
  int f32 = flag[0];
  int tm  = flag[1];
  int idx = blockIdx.x * blockDim.x + threadIdx.x;   // exactly NNODES*64 threads
  if (idx < NNODES){
    if (idx < NATOMS){
      float x = ldf(pos, idx*3+0, f32);
      float y = ldf(pos, idx*3+1, f32);
      float z = ldf(pos, idx*3+2, f32);
      node_pos[idx*3+0] = x; node_pos[idx*3+1] = y; node_pos[idx*3+2] = z;
      npd[idx*3+0] = (double)x; npd[idx*3+1] = (double)y; npd[idx*3+2] = (double)z;
    } else {
      int cell = (idx - NATOMS) % NG_PER;
      int ix = cell / 144, iy = (cell / 12) % 12, iz = cell % 12;
      double gx = -8.25 + 1.5 * ix, gy = -8.25 + 1.5 * iy, gz = -8.25 + 1.5 * iz;
      node_pos[idx*3+0] = (float)gx; node_pos[idx*3+1] = (float)gy; node_pos[idx*3+2] = (float)gz;
      npd[idx*3+0] = gx; npd[idx*3+1] = gy; npd[idx*3+2] = gz;
    }
  }
  int node = idx >> 6, c = idx & 63;
  float v = 0.f;
  if (node < NATOMS && c == ldt(types, node, tm)) v = 1.f;
  h0[idx] = v;
}

// ---------- atom-atom kNN (K=8), f32 no-FMA (matches numpy f32 d2 bitwise) ----------
__global__ void k_knn_atoms(const void* __restrict__ pos, const int* __restrict__ flag,
                            int* __restrict__ nbrA){
  #pragma clang fp contract(off)
  int f32 = flag[0];
  int i = blockIdx.x;                 // global atom id
  int b = i >> 8, li = i & 255;
  int l = threadIdx.x;                // 0..63
  float px = ldf(pos,3*i,f32), py = ldf(pos,3*i+1,f32), pz = ldf(pos,3*i+2,f32);
  float vals[4];
  for (int q = 0; q < 4; q++){
    int c = l + 64*q;
    int j = (b << 8) + c;
    float dx = ldf(pos,3*j+0,f32) - px;
    float dy = ldf(pos,3*j+1,f32) - py;
    float dz = ldf(pos,3*j+2,f32) - pz;
    float d2 = (dx*dx + dy*dy) + dz*dz;
    vals[q] = (c == li) ? INFINITY : d2;
  }
  for (int it = 0; it < KA; it++){
    float v = vals[0]; int idx = l;
    for (int q = 1; q < 4; q++){
      if (vals[q] < v){ v = vals[q]; idx = l + 64*q; }
    }
    for (int m = 1; m < 64; m <<= 1){
      float ov = __shfl_xor(v, m);
      int   oi = __shfl_xor(idx, m);
      if (ov < v || (ov == v && oi < idx)){ v = ov; idx = oi; }
    }
    if (l == 0) nbrA[i*KA + it] = (b << 8) + idx;
    if ((idx & 63) == l) vals[idx >> 6] = INFINITY;
  }
}

// ---------- grid->atom kNN (K=32), f64 exact (numpy grid coords are float64) ----------
__global__ void k_knn_grid(const double* __restrict__ npd, int* __restrict__ nbrG){
  int gi = blockIdx.x;                 // 0..NGRID-1
  int b = gi / NG_PER, cell = gi % NG_PER;
  int ix = cell / 144, iy = (cell / 12) % 12, iz = cell % 12;
  double px = -8.25 + 1.5 * ix;
  double py = -8.25 + 1.5 * iy;
  double pz = -8.25 + 1.5 * iz;
  int l = threadIdx.x;
  double vals[4];
  for (int q = 0; q < 4; q++){
    int c = l + 64*q;
    int j = (b << 8) + c;
    double dx = px - npd[3*j+0];
    double dy = py - npd[3*j+1];
    double dz = pz - npd[3*j+2];
    vals[q] = dx*dx + dy*dy + dz*dz;   // exact in f64 (all terms < 2^53)
  }
  for (int it = 0; it < KG; it++){
    double v = vals[0]; int idx = l;
    for (int q = 1; q < 4; q++){
      if (vals[q] < v){ v = vals[q]; idx = l + 64*q; }
    }
    for (int m = 1; m < 64; m <<= 1){
      double ov = __shfl_xor(v, m);
      int    oi = __shfl_xor(idx, m);
      if (ov < v || (ov == v && oi < idx)){ v = ov; idx = oi; }
    }
    if (l == 0) nbrG[gi*KG + it] = (b << 8) + idx;
    if ((idx & 63) == l) vals[idx >> 6] = INFINITY;
  }
}

// ---------- brute-force per-node layer: per-edge mi@W1, relu, sum, W2, LN ----------
template<int KK>
__global__ void __launch_bounds__(128) k_node(
    const float* __restrict__ hin, const int* __restrict__ nbr0,
    const double* __restrict__ npd, const double* __restrict__ gcd,
    const void* __restrict__ W1, const void* __restrict__ b1,
    const void* __restrict__ eW, const void* __restrict__ eb,
    const void* __restrict__ W2, const void* __restrict__ b2,
    const void* __restrict__ lng, const void* __restrict__ lnb,
    size_t w1o, size_t b1o, size_t eWo, size_t ebo, size_t w2o, size_t b2o,
    size_t go, size_t bo, const int* __restrict__ flag, int nodeBase,
    float* __restrict__ hout, float* __restrict__ out, int writeOut)
{
  __shared__ __attribute__((aligned(16))) float sHs[KK*64];  // h[src] rows
  __shared__ __attribute__((aligned(16))) float sEf[KK*64];  // edge features
  __shared__ float sW1t[16*128];                             // W1 row tile
  __shared__ float sG[KK*20];
  __shared__ float seW[20*64];
  __shared__ float sS[128];
  __shared__ float sHd[64];
  __shared__ double sDist[KK];
  __shared__ int sN[KK];
  int f32 = flag[0];
  int node = nodeBase + blockIdx.x;
  int t = threadIdx.x;                 // 128
  const int* nbr = nbr0 + (size_t)blockIdx.x * KK;
  if (t < KK) sN[t] = nbr[t];
  if (t < 64) sHd[t] = hin[(size_t)node*CODE + t];
  for (int i = t; i < 20*64; i += 128) seW[i] = ldf(eW, eWo + i, f32);
  __syncthreads();
  if (t < KK){
    int s = sN[t];
    double dx = npd[(size_t)s*3+0] - npd[(size_t)node*3+0];
    double dy = npd[(size_t)s*3+1] - npd[(size_t)node*3+1];
    double dz = npd[(size_t)s*3+2] - npd[(size_t)node*3+2];
    double d = sqrt(dx*dx + dy*dy + dz*dz);
    sDist[t] = (d > 5.0) ? 5.0 : d;
  }
  __syncthreads();
  for (int i = t; i < KK*20; i += 128){
    int e = i / 20, g = i - e*20;
    double dd = sDist[e] - gcd[g];
    sG[i] = (float)exp(gcd[20 + g] * dd * dd);
  }
  for (int i = t; i < KK*64; i += 128){
    int e = i >> 6, c = i & 63;
    sHs[i] = hin[(size_t)sN[e]*CODE + c];
  }
  __syncthreads();
  // per-edge edge-feature vector ef = gauss @ eW + eb
  for (int i = t; i < KK*64; i += 128){
    int e = i >> 6, c = i & 63;
    float acc = ldf(eb, ebo + c, f32);
    #pragma unroll
    for (int g = 0; g < 20; g++) acc = fmaf(sG[e*20 + g], seW[g*64 + c], acc);
    sEf[i] = acc;
  }
  // shared (dst) part of z: zd[t] = b1[t] + sum_i h[dst][i] * W1[64+i][t]
  float zd = ldf(b1, b1o + t, f32);
  for (int i = 0; i < 64; i++)
    zd = fmaf(sHd[i], ldf(W1, w1o + (size_t)(64 + i)*HID + t, f32), zd);
  __syncthreads();
  float z[KK];
  #pragma unroll
  for (int e = 0; e < KK; e++) z[e] = zd;
  // 8 tiles of 16 rows: tiles 0..3 -> W1 rows 0..63 (src h), 4..7 -> rows 128..191 (ef)
  for (int tile = 0; tile < 8; tile++){
    int rbase = (tile < 4) ? tile*16 : 128 + (tile - 4)*16;
    __syncthreads();
    for (int i = t; i < 16*128; i += 128)
      sW1t[i] = ldf(W1, w1o + (size_t)(rbase + (i >> 7))*HID + (i & 127), f32);
    __syncthreads();
    const float* mi = (tile < 4) ? sHs : sEf;
    int mbase = (tile < 4) ? tile*16 : (tile - 4)*16;
    #pragma unroll
    for (int e = 0; e < KK; e++){
      float acc = z[e];
      const float* mip = mi + e*64 + mbase;
      #pragma unroll
      for (int r4 = 0; r4 < 4; r4++){
        float4 mv = *(const float4*)(mip + 4*r4);
        acc = fmaf(mv.x, sW1t[(4*r4+0)*128 + t], acc);
        acc = fmaf(mv.y, sW1t[(4*r4+1)*128 + t], acc);
        acc = fmaf(mv.z, sW1t[(4*r4+2)*128 + t], acc);
        acc = fmaf(mv.w, sW1t[(4*r4+3)*128 + t], acc);
      }
      z[e] = acc;
    }
  }
  float S = 0.f;
  #pragma unroll
  for (int e = 0; e < KK; e++) S += fmaxf(z[e], 0.f);
  sS[t] = S * (1.f / KK);
  __syncthreads();
  if (t < CODE){
    float acc = 0.f;
    for (int k = 0; k < HID; k++)
      acc = fmaf(sS[k], ldf(W2, w2o + (size_t)k*CODE + t, f32), acc);
    float x = hin[(size_t)node*CODE + t] + acc + ldf(b2, b2o + t, f32);
    float s = x;
    #pragma unroll
    for (int m = 1; m < 64; m <<= 1) s += __shfl_xor(s, m);
    float mu = s * (1.f/64.f);
    float d = x - mu;
    float v = d * d;
    #pragma unroll
    for (int m = 1; m < 64; m <<= 1) v += __shfl_xor(v, m);
    v *= (1.f/64.f);
    float o = d / sqrtf(v + 1e-5f) * ldf(lng, go + t, f32) + ldf(lnb, bo + t, f32);
    hout[(size_t)node*CODE + t] = o;
    if (writeOut && node >= NATOMS)
      out[(size_t)(node - NATOMS)*CODE + t] = o;   // OUTPUT IS FLOAT32 (ref dtype)
  }
}

extern "C" void kernel_launch(void* const* d_in, const int* in_sizes, int n_in,
                              void* d_out, int out_size, void* d_ws, size_t ws_size,
                              hipStream_t stream) {
  const void* pos    = d_in[0];
  const void* types  = d_in[1];
  // d_in[2] = batch (unused by the math)
  const void* edge_W = d_in[3];
  const void* edge_b = d_in[4];
  const void* W1     = d_in[5];
  const void* b1     = d_in[6];
  const void* W2     = d_in[7];
  const void* b2     = d_in[8];
  const void* lng    = d_in[9];
  const void* lnb    = d_in[10];

  const size_t NEED = (size_t)7 * 1024 * 1024;
  char* w = (ws_size >= NEED) ? (char*)d_ws : (char*)g_buf;
  if (w == nullptr) w = (char*)d_ws;   // last resort

  size_t o = 0;
  auto alloc = [&](size_t bytes)->char*{
    char* r = w + o; o = (o + bytes + 255) & ~(size_t)255; return r;
  };
  float*  node_pos = (float*) alloc((size_t)NNODES*3*4);
  double* npd      = (double*)alloc((size_t)NNODES*3*8);
  float*  hA       = (float*) alloc((size_t)NNODES*CODE*4);
  float*  hB       = (float*) alloc((size_t)NNODES*CODE*4);
  int*    nbrA     = (int*)   alloc((size_t)NATOMS*KA*4);
  int*    nbrG     = (int*)   alloc((size_t)NGRID*KG*4);
  double* gcd      = (double*)alloc(40*8);
  int*    flag     = (int*)   alloc(64*4);

  k_detect<<<2, 256, 0, stream>>>((const unsigned short*)pos,
                                  (const unsigned short*)types, flag);
  k_consts<<<1, 32, 0, stream>>>(gcd);
  k_init<<<(NNODES*CODE)/256, 256, 0, stream>>>(pos, types, flag, node_pos, npd, hA);
  k_knn_atoms<<<NATOMS, 64, 0, stream>>>(pos, flag, nbrA);
  k_knn_grid<<<NGRID, 64, 0, stream>>>(npd, nbrG);

  float* hin = hA; float* hout = hB;
  for (int l = 0; l < 4; l++){
    size_t wl  = (size_t)l*192*128;
    size_t eWo = (size_t)l*20*64, ebo = (size_t)l*64;
    size_t b1o = (size_t)l*128,   w2o = (size_t)l*128*64;
    size_t b2o = (size_t)l*64,    lno = (size_t)l*64;
    k_node<KA><<<NATOMS, 128, 0, stream>>>(hin, nbrA, npd, gcd,
        W1, b1, edge_W, edge_b, W2, b2, lng, lnb,
        wl, b1o, eWo, ebo, w2o, b2o, lno, lno, flag, 0,
        hout, (float*)d_out, 0);
    k_node<KG><<<NGRID, 128, 0, stream>>>(hin, nbrG, npd, gcd,
        W1, b1, edge_W, edge_b, W2, b2, lng, lnb,
        wl, b1o, eWo, ebo, w2o, b2o, lno, lno, flag, NATOMS,
        hout, (float*)d_out, (l == 3) ? 1 : 0);
    float* tmp = hin; hin = hout; hout = tmp;
  }
}

// Round 7
// 576.770 us; speedup vs baseline: 3.7262x; 3.7262x over previous
//
#include <hip/hip_runtime.h>
#include <hip/hip_bf16.h>
#include <math.h>

#define NATOMS 1024          // B*A
#define NGRID  6912          // B*NG
#define NNODES 7936
#define NG_PER 1728
#define KA 8
#define KG 32
#define CODE 64
#define HID 128

typedef __hip_bfloat16 bf16;

// Fallback workspace allocated at library load (legal: outside kernel_launch).
static void* g_buf = nullptr;
__attribute__((constructor)) static void _alloc_ws(){
  if (hipMalloc(&g_buf, (size_t)24 * 1024 * 1024) != hipSuccess) g_buf = nullptr;
}

// dtype-agnostic float load: element i of buffer p, fp32 if f32!=0 else bf16
__device__ __forceinline__ float ldf(const void* p, size_t i, int f32){
  return f32 ? ((const float*)p)[i] : __bfloat162float(((const bf16*)p)[i]);
}

// dtype-agnostic int load: mode 0=int32, 1=int64(LE), 2=f32, 3=bf16
__device__ __forceinline__ int ldt(const void* p, int i, int mode){
  switch(mode){
    case 1:  return ((const int*)p)[2*i];
    case 2:  return (int)((const float*)p)[i];
    case 3:  return (int)__bfloat162float(((const bf16*)p)[i]);
    default: return ((const int*)p)[i];
  }
}

// ---------- detect input dtypes (pos float width, atom_types int width) ----------
__global__ void k_detect(const unsigned short* __restrict__ posu,
                         const unsigned short* __restrict__ typu,
                         int* __restrict__ flag){
  if (blockIdx.x == 0){
    __shared__ int scnt;
    int t = threadIdx.x;               // 256 threads
    if (t == 0) scnt = 0;
    __syncthreads();
    int c = 0;
    for (int q = 0; q < 12; q++){
      unsigned short u = posu[t + 256*q];
      int e = (u >> 7) & 0xFF;
      if (e >= 140) c++;
    }
    atomicAdd(&scnt, c);
    __syncthreads();
    if (t == 0) flag[0] = (scnt > 16) ? 1 : 0;
  } else if (threadIdx.x == 0){
    int oddHigh = 0, evenHigh = 0, quadZero = 1;
    for (int k = 0; k < 16; k++){
      unsigned short o = typu[2*k+1], e = typu[2*k];
      if (o >= 0x3F00 && o <= 0x4200) oddHigh++;
      if (e >= 0x3F00 && e <= 0x4200) evenHigh++;
    }
    for (int k = 0; k < 16; k++) if (typu[4*k+2] != 0) quadZero = 0;
    int mode;
    if (oddHigh >= 8) mode = (evenHigh >= 8) ? 3 : 2;   // bf16 : f32
    else              mode = quadZero ? 1 : 0;          // int64 : int32
    flag[1] = mode;
  }
}

// ---------- gaussian smearing constants (f64 internally, f32 out) ----------
__global__ void k_consts(float* offc){
  int k = threadIdx.x;
  if (k >= 20) return;
  double step = log(6.0) / 19.0;
  double offk = exp((double)k * step) - 1.0;
  int km = (k == 0) ? 1 : k;
  double d = (exp((double)km * step) - 1.0) - (exp((double)(km - 1) * step) - 1.0);
  offc[k]      = (float)offk;
  offc[20 + k] = (float)(-0.5 / (d * d));
}

// ---------- node_pos (f32 + f64) + h0 (one-hot atoms, zero grid) ----------
__global__ void k_init(const void* __restrict__ pos, const void* __restrict__ types,
                       const int* __restrict__ flag,
                       float* __restrict__ node_pos, double* __restrict__ npd,
                       float* __restrict__ h0){
  int f32 = flag[0];
  int tm  = flag[1];
  int idx = blockIdx.x * blockDim.x + threadIdx.x;   // exactly NNODES*64 threads
  if (idx < NNODES){
    if (idx < NATOMS){
      float x = ldf(pos, idx*3+0, f32);
      float y = ldf(pos, idx*3+1, f32);
      float z = ldf(pos, idx*3+2, f32);
      node_pos[idx*3+0] = x; node_pos[idx*3+1] = y; node_pos[idx*3+2] = z;
      npd[idx*3+0] = (double)x; npd[idx*3+1] = (double)y; npd[idx*3+2] = (double)z;
    } else {
      int cell = (idx - NATOMS) % NG_PER;
      int ix = cell / 144, iy = (cell / 12) % 12, iz = cell % 12;
      double gx = -8.25 + 1.5 * ix, gy = -8.25 + 1.5 * iy, gz = -8.25 + 1.5 * iz;
      node_pos[idx*3+0] = (float)gx; node_pos[idx*3+1] = (float)gy; node_pos[idx*3+2] = (float)gz;
      npd[idx*3+0] = gx; npd[idx*3+1] = gy; npd[idx*3+2] = gz;
    }
  }
  int node = idx >> 6, c = idx & 63;
  float v = 0.f;
  if (node < NATOMS && c == ldt(types, node, tm)) v = 1.f;
  h0[idx] = v;
}

// ---------- atom-atom kNN (K=8), f32 no-FMA (matches numpy f32 d2) ----------
__global__ void k_knn_atoms(const void* __restrict__ pos, const int* __restrict__ flag,
                            int* __restrict__ nbrA){
  #pragma clang fp contract(off)
  int f32 = flag[0];
  int i = blockIdx.x;                 // global atom id
  int b = i >> 8, li = i & 255;
  int l = threadIdx.x;                // 0..63
  float px = ldf(pos,3*i,f32), py = ldf(pos,3*i+1,f32), pz = ldf(pos,3*i+2,f32);
  float vals[4];
  for (int q = 0; q < 4; q++){
    int c = l + 64*q;
    int j = (b << 8) + c;
    float dx = ldf(pos,3*j+0,f32) - px;
    float dy = ldf(pos,3*j+1,f32) - py;
    float dz = ldf(pos,3*j+2,f32) - pz;
    float d2 = (dx*dx + dy*dy) + dz*dz;
    vals[q] = (c == li) ? INFINITY : d2;
  }
  for (int it = 0; it < KA; it++){
    float v = vals[0]; int idx = l;
    for (int q = 1; q < 4; q++){
      if (vals[q] < v){ v = vals[q]; idx = l + 64*q; }
    }
    for (int m = 1; m < 64; m <<= 1){
      float ov = __shfl_xor(v, m);
      int   oi = __shfl_xor(idx, m);
      if (ov < v || (ov == v && oi < idx)){ v = ov; idx = oi; }
    }
    if (l == 0) nbrA[i*KA + it] = (b << 8) + idx;
    if ((idx & 63) == l) vals[idx >> 6] = INFINITY;
  }
}

// ---------- grid->atom kNN (K=32), f64 exact (numpy grid coords are float64) ----------
__global__ void k_knn_grid(const double* __restrict__ npd, int* __restrict__ nbrG){
  int gi = blockIdx.x;                 // 0..NGRID-1
  int b = gi / NG_PER, cell = gi % NG_PER;
  int ix = cell / 144, iy = (cell / 12) % 12, iz = cell % 12;
  double px = -8.25 + 1.5 * ix;
  double py = -8.25 + 1.5 * iy;
  double pz = -8.25 + 1.5 * iz;
  int l = threadIdx.x;
  double vals[4];
  for (int q = 0; q < 4; q++){
    int c = l + 64*q;
    int j = (b << 8) + c;
    double dx = px - npd[3*j+0];
    double dy = py - npd[3*j+1];
    double dz = pz - npd[3*j+2];
    vals[q] = dx*dx + dy*dy + dz*dz;   // exact in f64
  }
  for (int it = 0; it < KG; it++){
    double v = vals[0]; int idx = l;
    for (int q = 1; q < 4; q++){
      if (vals[q] < v){ v = vals[q]; idx = l + 64*q; }
    }
    for (int m = 1; m < 64; m <<= 1){
      double ov = __shfl_xor(v, m);
      int    oi = __shfl_xor(idx, m);
      if (ov < v || (ov == v && oi < idx)){ v = ov; idx = oi; }
    }
    if (l == 0) nbrG[gi*KG + it] = (b << 8) + idx;
    if ((idx & 63) == l) vals[idx >> 6] = INFINITY;
  }
}

// ---------- fused per-layer folds: Xd = h@W1dst (all), Xs = h@W1src (atoms),
//            Wg = eW@W1c, b1p = b1 + eb@W1c.  561 blocks x 128 threads ----------
__global__ void __launch_bounds__(128) k_fold(const float* __restrict__ hin,
    const void* __restrict__ W1, const void* __restrict__ b1,
    const void* __restrict__ eW, const void* __restrict__ eb,
    size_t wl, size_t b1o, size_t eWo, size_t ebo,
    const int* __restrict__ flag,
    float* __restrict__ Xd, float* __restrict__ Xs,
    float* __restrict__ Wg, float* __restrict__ b1p)
{
  __shared__ float sW[64*128];
  __shared__ float sA[1344];
  int f32 = flag[0];
  int t = threadIdx.x;
  int b = blockIdx.x;
  if (b < 560){
    int isXd = (b < 496);
    size_t wo = wl + (isXd ? (size_t)64*128 : 0);
    int r0 = (isXd ? b : (b - 496)) * 16;
    float* C = isXd ? Xd : Xs;
    for (int i = t; i < 64*128; i += 128) sW[i] = ldf(W1, wo + i, f32);
    for (int i = t; i < 16*64;  i += 128) sA[i] = hin[(size_t)r0*64 + i];
    __syncthreads();
    for (int r = 0; r < 16; r++){
      float acc = 0.f;
      #pragma unroll
      for (int k = 0; k < 64; k++) acc = fmaf(sA[r*64+k], sW[k*128+t], acc);
      C[(size_t)(r0 + r)*128 + t] = acc;
    }
  } else {
    for (int i = t; i < 64*128; i += 128) sW[i] = ldf(W1, wl + (size_t)128*128 + i, f32);
    for (int i = t; i < 20*64;  i += 128) sA[i] = ldf(eW, eWo + i, f32);
    if (t < 64) sA[1280 + t] = ldf(eb, ebo + t, f32);
    __syncthreads();
    for (int g = 0; g < 20; g++){
      float acc = 0.f;
      #pragma unroll
      for (int k = 0; k < 64; k++) acc = fmaf(sA[g*64+k], sW[k*128+t], acc);
      Wg[g*128 + t] = acc;
    }
    float acc = ldf(b1, b1o + t, f32);
    #pragma unroll
    for (int k = 0; k < 64; k++) acc = fmaf(sA[1280+k], sW[k*128+t], acc);
    b1p[t] = acc;
  }
}

// ---------- aggregation: Sbuf[node][t] = (1/K) sum_e relu(Xd+Xs[src]+b1p+g@Wg)
//            blocks 0..63: 16 atoms each (K=8); 64..927: 8 grid nodes (K=32) ----------
__global__ void __launch_bounds__(128) k_aggr(const float* __restrict__ Xs,
    const float* __restrict__ Xd, const int* __restrict__ nbrA,
    const int* __restrict__ nbrG, const float* __restrict__ node_pos,
    const float* __restrict__ offc, const float* __restrict__ Wg,
    const float* __restrict__ b1p, float* __restrict__ Sbuf)
{
  __shared__ float sWg[20*128];   // 10 KB
  __shared__ float sG[256*20];    // 20 KB
  __shared__ float sD[256];
  __shared__ int   sN[256];
  __shared__ float sOff[40];
  int t = threadIdx.x;
  int b = blockIdx.x;
  int NPB, KK, node0; const int* nbr;
  if (b < 64){ NPB = 16; KK = 8;  node0 = b*16;              nbr = nbrA + b*16*8; }
  else       { NPB = 8;  KK = 32; node0 = NATOMS + (b-64)*8; nbr = nbrG + (size_t)(b-64)*8*32; }
  int nE = NPB * KK;              // 128 or 256
  for (int i = t; i < 20*128; i += 128) sWg[i] = Wg[i];
  if (t < 40) sOff[t] = offc[t];
  for (int i = t; i < nE; i += 128) sN[i] = nbr[i];
  __syncthreads();
  for (int i = t; i < nE; i += 128){
    int node = node0 + i / KK, src = sN[i];
    float dx = node_pos[src*3+0] - node_pos[node*3+0];
    float dy = node_pos[src*3+1] - node_pos[node*3+1];
    float dz = node_pos[src*3+2] - node_pos[node*3+2];
    sD[i] = fminf(sqrtf(dx*dx + dy*dy + dz*dz), 5.0f);
  }
  __syncthreads();
  for (int i = t; i < nE*20; i += 128){
    int e = i / 20, k = i - e*20;
    float dd = sD[e] - sOff[k];
    sG[i] = expf(sOff[20+k] * dd * dd);
  }
  float b1v = b1p[t];
  __syncthreads();
  float rK = 1.f / KK;
  for (int n = 0; n < NPB; n++){
    int node = node0 + n;
    float zb = Xd[(size_t)node*128 + t] + b1v;
    float S = 0.f;
    for (int e = 0; e < KK; e++){
      int idx = n*KK + e;
      float acc = zb + Xs[(size_t)sN[idx]*128 + t];
      const float* gg = &sG[idx*20];
      #pragma unroll
      for (int k = 0; k < 20; k++) acc = fmaf(gg[k], sWg[k*128+t], acc);
      S += fmaxf(acc, 0.f);
    }
    Sbuf[(size_t)node*128 + t] = S * rK;
  }
}

// ---------- output: x = hin + Sbuf@W2 + b2 -> LayerNorm; 16 rows/block ----------
__global__ void __launch_bounds__(128) k_out(const float* __restrict__ hin,
    const float* __restrict__ Sbuf,
    const void* __restrict__ W2, const void* __restrict__ b2,
    const void* __restrict__ lng, const void* __restrict__ lnb,
    size_t w2o, size_t b2o, size_t lno,
    const int* __restrict__ flag,
    float* __restrict__ hout, float* __restrict__ out, int writeOut)
{
  __shared__ float sW2[128*64];   // 32 KB
  __shared__ float sS[16*128];    // 8 KB
  int f32 = flag[0];
  int t = threadIdx.x;
  int r0 = blockIdx.x * 16;
  for (int i = t; i < 128*64; i += 128) sW2[i] = ldf(W2, w2o + i, f32);
  for (int i = t; i < 16*128; i += 128) sS[i] = Sbuf[(size_t)r0*128 + i];
  int w = t >> 6, c = t & 63;
  float b2v = ldf(b2, b2o + c, f32);
  float gv  = ldf(lng, lno + c, f32);
  float bv  = ldf(lnb, lno + c, f32);
  __syncthreads();
  for (int rr = w; rr < 16; rr += 2){
    int node = r0 + rr;
    float acc = 0.f;
    const float* ss = &sS[rr*128];
    #pragma unroll
    for (int k = 0; k < 128; k++) acc = fmaf(ss[k], sW2[k*64+c], acc);
    float x = hin[(size_t)node*64 + c] + acc + b2v;
    float s = x;
    #pragma unroll
    for (int m = 1; m < 64; m <<= 1) s += __shfl_xor(s, m);
    float mu = s * (1.f/64.f);
    float d = x - mu;
    float v = d * d;
    #pragma unroll
    for (int m = 1; m < 64; m <<= 1) v += __shfl_xor(v, m);
    v *= (1.f/64.f);
    float o = d / sqrtf(v + 1e-5f) * gv + bv;
    hout[(size_t)node*64 + c] = o;
    if (writeOut && node >= NATOMS) out[(size_t)(node - NATOMS)*64 + c] = o;
  }
}

extern "C" void kernel_launch(void* const* d_in, const int* in_sizes, int n_in,
                              void* d_out, int out_size, void* d_ws, size_t ws_size,
                              hipStream_t stream) {
  const void* pos    = d_in[0];
  const void* types  = d_in[1];
  // d_in[2] = batch (unused by the math)
  const void* edge_W = d_in[3];
  const void* edge_b = d_in[4];
  const void* W1     = d_in[5];
  const void* b1     = d_in[6];
  const void* W2     = d_in[7];
  const void* b2     = d_in[8];
  const void* lng    = d_in[9];
  const void* lnb    = d_in[10];

  const size_t NEED = (size_t)16 * 1024 * 1024;
  char* w = (ws_size >= NEED) ? (char*)d_ws : (char*)g_buf;
  if (w == nullptr) w = (char*)d_ws;   // last resort

  size_t o = 0;
  auto alloc = [&](size_t bytes)->char*{
    char* r = w + o; o = (o + bytes + 255) & ~(size_t)255; return r;
  };
  float*  node_pos = (float*) alloc((size_t)NNODES*3*4);
  double* npd      = (double*)alloc((size_t)NNODES*3*8);
  float*  hA       = (float*) alloc((size_t)NNODES*CODE*4);
  float*  hB       = (float*) alloc((size_t)NNODES*CODE*4);
  float*  Xs       = (float*) alloc((size_t)NATOMS*HID*4);
  float*  Xd       = (float*) alloc((size_t)NNODES*HID*4);
  float*  Sbuf     = (float*) alloc((size_t)NNODES*HID*4);
  int*    nbrA     = (int*)   alloc((size_t)NATOMS*KA*4);
  int*    nbrG     = (int*)   alloc((size_t)NGRID*KG*4);
  float*  offc     = (float*) alloc(64*4);
  float*  Wg       = (float*) alloc(20*HID*4);
  float*  b1p      = (float*) alloc(HID*4);
  int*    flag     = (int*)   alloc(64*4);

  k_detect<<<2, 256, 0, stream>>>((const unsigned short*)pos,
                                  (const unsigned short*)types, flag);
  k_consts<<<1, 32, 0, stream>>>(offc);
  k_init<<<(NNODES*CODE)/256, 256, 0, stream>>>(pos, types, flag, node_pos, npd, hA);
  k_knn_atoms<<<NATOMS, 64, 0, stream>>>(pos, flag, nbrA);
  k_knn_grid<<<NGRID, 64, 0, stream>>>(npd, nbrG);

  float* hin = hA; float* hout = hB;
  for (int l = 0; l < 4; l++){
    size_t wl  = (size_t)l*192*128;
    size_t eWo = (size_t)l*20*64, ebo = (size_t)l*64;
    size_t b1o = (size_t)l*128,   w2o = (size_t)l*128*64;
    size_t b2o = (size_t)l*64,    lno = (size_t)l*64;
    k_fold<<<561, 128, 0, stream>>>(hin, W1, b1, edge_W, edge_b,
                                    wl, b1o, eWo, ebo, flag, Xd, Xs, Wg, b1p);
    k_aggr<<<64 + NGRID/8, 128, 0, stream>>>(Xs, Xd, nbrA, nbrG, node_pos,
                                             offc, Wg, b1p, Sbuf);
    k_out<<<NNODES/16, 128, 0, stream>>>(hin, Sbuf, W2, b2, lng, lnb,
                                         w2o, b2o, lno, flag,
                                         hout, (float*)d_out, (l == 3) ? 1 : 0);
    float* tmp = hin; hin = hout; hout = tmp;
  }
}